// Round 15
// baseline (192.161 us; speedup 1.0000x reference)
//
#include <hip/hip_runtime.h>
#include <hip/hip_bf16.h>
#include <stdint.h>

// Round 15: conv kernel fission. conv_q (27 wgt, ~85 live regs, z-chunks x4,
// 6144 blocks) + conv_kv (54 wgt, 3x3x3 window, ~90 live). Separate kernels =
// separate regalloc contexts (R6's in-kernel split shared one and remat'd).
// attn (R14) / GEMMs frozen.

typedef _Float16 f16;
typedef _Float16 f16x8 __attribute__((ext_vector_type(8)));
typedef float f32x4 __attribute__((ext_vector_type(4)));
typedef float f32x16 __attribute__((ext_vector_type(16)));
typedef uint32_t u32;
typedef uint32_t u32x4 __attribute__((ext_vector_type(4)));

#define NC 384
#define MFMA16(A_,B_,C_) __builtin_amdgcn_mfma_f32_16x16x32_f16((A_),(B_),(C_),0,0,0)
#define MFMA32(A_,B_,C_) __builtin_amdgcn_mfma_f32_32x32x16_f16((A_),(B_),(C_),0,0,0)

__device__ __forceinline__ void gll16(const void* g, void* l) {
  __builtin_amdgcn_global_load_lds(
      (__attribute__((address_space(1))) void*)g,
      (__attribute__((address_space(3))) void*)l, 16, 0, 0);
}

__device__ __forceinline__ u32 pkf16(float lo, float hi) {
  return __builtin_bit_cast(u32, __builtin_amdgcn_cvt_pkrtz(lo, hi));
}

// ---------------- weight fp32 -> f16 convert (scq folded into wq) ----------------
__global__ __launch_bounds__(256) void cvt_w(
    const float* __restrict__ s0, const float* __restrict__ s1,
    const float* __restrict__ s2, const float* __restrict__ s3,
    f16* __restrict__ d0, f16* __restrict__ d1,
    f16* __restrict__ d2, f16* __restrict__ d3, int n, float scq)
{
  int i = blockIdx.x * 256 + threadIdx.x;
  if (i < n) {
    d0[i] = (f16)(s0[i] * scq);
    d1[i] = (f16)s1[i]; d2[i] = (f16)s2[i]; d3[i] = (f16)s3[i];
  }
}

// ---------------- conv-weight transpose [384][27] -> [27][384] ----------------
__global__ __launch_bounds__(384) void cvt_wt(
    const float* __restrict__ wq, const float* __restrict__ wk, const float* __restrict__ wv,
    float* __restrict__ qT, float* __restrict__ kT, float* __restrict__ vT)
{
  const int c = threadIdx.x;
  const int t = blockIdx.x;
  qT[t * 384 + c] = wq[c * 27 + t];
  kT[t * 384 + c] = wk[c * 27 + t];
  vT[t * 384 + c] = wv[c * 27 + t];
}

// ---------------- conv_q: depthwise conv3d stride1 + BN (27 wgt, z-chunks x4) ----------------
// 128 thr (2 waves); grid (64 tiles x 3 c-thirds, 8 b, 4 z-chunks).
__global__ __launch_bounds__(128) void conv_q(
    const float* __restrict__ x, const float* __restrict__ wqT,
    const float* __restrict__ bqg, const float* __restrict__ bqb,
    const float* __restrict__ bqm, const float* __restrict__ bqv,
    f16* __restrict__ qout)
{
  const int tile = blockIdx.x / 3, cthird = blockIdx.x % 3;
  const int c = cthird * 128 + threadIdx.x;
  const int th = tile >> 3, tw = tile & 7;
  const int b = blockIdx.y;
  const int z0 = blockIdx.z * 4;
  const int h0 = th * 2, w0 = tw * 2;

  float wqr[27];
#pragma unroll
  for (int t = 0; t < 27; ++t) wqr[t] = wqT[t * 384 + c];
  const float invq = bqg[c] * rsqrtf(bqv[c] + 1e-5f);
  const float betq = bqb[c] - bqm[c] * invq;

  bool hok[4], wok[4];
#pragma unroll
  for (int a = 0; a < 4; ++a) {
    hok[a] = (unsigned)(h0 - 1 + a) < 16u;
    wok[a] = (unsigned)(w0 - 1 + a) < 16u;
  }
  const float* xb = x + (size_t)b * 4096 * NC + c;

  float win[3][4][4];
  auto ldplane = [&](int s, int iz) {   // s compile-time after unroll
    const bool zok = (unsigned)iz < 16u;
#pragma unroll
    for (int a = 0; a < 4; ++a)
#pragma unroll
      for (int e = 0; e < 4; ++e) {
        float v = 0.f;
        if (zok && hok[a] && wok[e])
          v = xb[(size_t)((h0 - 1 + a) * 256 + (w0 - 1 + e) * 16 + iz) * NC];
        win[s][a][e] = v;
      }
  };
  // plane t = z0-1+t -> slot t%3; prologue t=0,1
  ldplane(0, z0 - 1);
  ldplane(1, z0);

#pragma unroll
  for (int zr = 0; zr < 4; ++zr) {
    const int z = z0 + zr;
    ldplane((zr + 2) % 3, z + 1);   // t = zr+2
    float aq00 = 0.f, aq01 = 0.f, aq10 = 0.f, aq11 = 0.f;
#pragma unroll
    for (int p = 0; p < 3; ++p) {
      const int s = (zr + p) % 3;   // t = zr+p
#pragma unroll
      for (int a = 0; a < 3; ++a)
#pragma unroll
        for (int e = 0; e < 3; ++e) {
          const float cq = wqr[a * 9 + e * 3 + p];
          aq00 += win[s][a][e]         * cq;
          aq01 += win[s][a][e + 1]     * cq;
          aq10 += win[s][a + 1][e]     * cq;
          aq11 += win[s][a + 1][e + 1] * cq;
        }
    }
    const size_t qb = (size_t)b * 4096;
    qout[(qb + (h0 + 0) * 256 + (w0 + 0) * 16 + z) * NC + c] = (f16)(aq00 * invq + betq);
    qout[(qb + (h0 + 0) * 256 + (w0 + 1) * 16 + z) * NC + c] = (f16)(aq01 * invq + betq);
    qout[(qb + (h0 + 1) * 256 + (w0 + 0) * 16 + z) * NC + c] = (f16)(aq10 * invq + betq);
    qout[(qb + (h0 + 1) * 256 + (w0 + 1) * 16 + z) * NC + c] = (f16)(aq11 * invq + betq);
  }
}

// ---------------- conv_kv: depthwise conv3d stride2 + BN (3x3x3 window) ----------------
// 128 thr; grid (64 tiles x 3 c-thirds, 8 b, 2 z-chunks of 4 kv-outputs).
__global__ __launch_bounds__(128) void conv_kv(
    const float* __restrict__ x,
    const float* __restrict__ wkT, const float* __restrict__ wvT,
    const float* __restrict__ bkg, const float* __restrict__ bkb,
    const float* __restrict__ bkm, const float* __restrict__ bkv,
    const float* __restrict__ bvg, const float* __restrict__ bvb,
    const float* __restrict__ bvm, const float* __restrict__ bvv,
    f16* __restrict__ kout, f16* __restrict__ vout)
{
  const int tile = blockIdx.x / 3, cthird = blockIdx.x % 3;
  const int c = cthird * 128 + threadIdx.x;
  const int th = tile >> 3, tw = tile & 7;
  const int b = blockIdx.y;
  const int z0 = blockIdx.z * 8;
  const int h0 = th * 2, w0 = tw * 2;

  float wkr[27], wvr[27];
#pragma unroll
  for (int t = 0; t < 27; ++t) { wkr[t] = wkT[t * 384 + c]; wvr[t] = wvT[t * 384 + c]; }
  const float invk = bkg[c] * rsqrtf(bkv[c] + 1e-5f), betk = bkb[c] - bkm[c] * invk;
  const float invv = bvg[c] * rsqrtf(bvv[c] + 1e-5f), betv = bvb[c] - bvm[c] * invv;

  bool hok[3], wok[3];
#pragma unroll
  for (int a = 0; a < 3; ++a) {
    hok[a] = (unsigned)(h0 - 1 + a) < 16u;
    wok[a] = (unsigned)(w0 - 1 + a) < 16u;
  }
  const float* xb = x + (size_t)b * 4096 * NC + c;

  float wn[3][3][3];
  auto ldplane3 = [&](int s, int iz) {
    const bool zok = (unsigned)iz < 16u;
#pragma unroll
    for (int a = 0; a < 3; ++a)
#pragma unroll
      for (int e = 0; e < 3; ++e) {
        float v = 0.f;
        if (zok && hok[a] && wok[e])
          v = xb[(size_t)((h0 - 1 + a) * 256 + (w0 - 1 + e) * 16 + iz) * NC];
        wn[s][a][e] = v;
      }
  };
  // plane j = z0-1+j -> slot j%3; prologue j=0,1,2
  ldplane3(0, z0 - 1);
  ldplane3(1, z0);
  ldplane3(2, z0 + 1);
#pragma unroll
  for (int i = 0; i < 4; ++i) {
    float ak = 0.f, av = 0.f;
#pragma unroll
    for (int p = 0; p < 3; ++p) {
      const int s = (2 * i + p) % 3;   // plane j = 2i+p
#pragma unroll
      for (int a = 0; a < 3; ++a)
#pragma unroll
        for (int e = 0; e < 3; ++e) {
          const float wv_ = wn[s][a][e];
          ak += wv_ * wkr[a * 9 + e * 3 + p];
          av += wv_ * wvr[a * 9 + e * 3 + p];
        }
    }
    const int zc = z0 + 2 * i;
    const size_t t = (size_t)b * 512 + (th * 8 + tw) * 8 + (zc >> 1);
    kout[t * NC + c] = (f16)(ak * invk + betk);
    vout[t * NC + c] = (f16)(av * invv + betv);
    if (i < 3) {
      ldplane3((2 * i + 3) % 3, zc + 2);
      ldplane3((2 * i + 4) % 3, zc + 3);
    }
  }
}

// ---------------- GEMM (R8 version): gll16 staging + XOR-swizzled LDS ----------------
template<int MODE>
__global__ __launch_bounds__(256) void gemm_bt(
    const f16* __restrict__ A, const f16* __restrict__ Bw,
    void* __restrict__ Cout, const float* __restrict__ bias)
{
  __shared__ f16 As[128 * 64];
  __shared__ f16 Bs[128 * 64];
  const int tid = threadIdx.x;
  const int w = tid >> 6, lane = tid & 63;
  const int g = lane >> 4, q = lane & 15;
  const int wr = w >> 1, wc = w & 1;
  const size_t brow = (size_t)blockIdx.y * 128;
  const int bcol = blockIdx.x * 128;
  const int srow = lane >> 3;
  const int sbb  = (lane & 7) ^ (srow & 7);
  f32x4 acc[4][4] = {};
  for (int kt = 0; kt < 6; ++kt) {
    const int k0 = kt * 64;
#pragma unroll
    for (int j = 0; j < 4; ++j) {
      const int s = w * 4 + j;
      gll16(A  + (brow + (size_t)(s * 8 + srow)) * NC + k0 + sbb * 8, (char*)As + s * 1024);
      gll16(Bw + (size_t)(bcol + s * 8 + srow) * NC + k0 + sbb * 8, (char*)Bs + s * 1024);
    }
    __syncthreads();
#pragma unroll
    for (int ks = 0; ks < 2; ++ks) {
      f16x8 af[4], bfr[4];
      const int bb = ((g + 4 * ks) ^ (q & 7)) * 16;
#pragma unroll
      for (int m = 0; m < 4; ++m) {
        af[m]  = *(const f16x8*)((const char*)As + (wr * 64 + m * 16 + q) * 128 + bb);
        bfr[m] = *(const f16x8*)((const char*)Bs + (wc * 64 + m * 16 + q) * 128 + bb);
      }
#pragma unroll
      for (int m = 0; m < 4; ++m)
#pragma unroll
        for (int n = 0; n < 4; ++n)
          acc[m][n] = MFMA16(af[m], bfr[n], acc[m][n]);
    }
    __syncthreads();
  }
  float bvals[4];
  if (MODE == 2) {
#pragma unroll
    for (int n = 0; n < 4; ++n) bvals[n] = bias[bcol + wc * 64 + n * 16 + q];
  }
#pragma unroll
  for (int m = 0; m < 4; ++m) {
#pragma unroll
    for (int n = 0; n < 4; ++n) {
#pragma unroll
      for (int r = 0; r < 4; ++r) {
        const size_t row = brow + wr * 64 + m * 16 + 4 * g + r;
        const int col = bcol + wc * 64 + n * 16 + q;
        const float v = acc[m][n][r];
        if (MODE == 0) {
          ((f16*)Cout)[row * NC + col] = (f16)v;
        } else if (MODE == 1) {
          const size_t bi = row >> 9, t = row & 511;
          ((f16*)Cout)[(bi * NC + col) * 512 + t] = (f16)v;
        } else {
          ((float*)Cout)[row * NC + col] = v + bvals[n];
        }
      }
    }
  }
}

// ---------------- flash attention (R14): per-half pipeline, unbiased exp2 ----------------
__global__ __launch_bounds__(256) void attn(
    const f16* __restrict__ Qp, const f16* __restrict__ Kp,
    const f16* __restrict__ Vt, f16* __restrict__ O)
{
  __shared__ f16 Ks[2][64 * 64];
  __shared__ f16 Vs[2][64 * 64];
  const int tid = threadIdx.x;
  const int w = tid >> 6, lane = tid & 63;
  const int c = lane & 31, h = lane >> 5;
  const int qt = blockIdx.x, hh = blockIdx.y, b = blockIdx.z;
  const size_t qrow = (size_t)b * 4096 + qt * 128 + w * 32 + c;

  f16x8 qf[4];
#pragma unroll
  for (int ks = 0; ks < 4; ++ks)
    qf[ks] = *(const f16x8*)(Qp + qrow * NC + hh * 64 + ks * 16 + 8 * h);

  f32x16 oa0 = {}, oa1 = {};
  float l_run = 0.f;

  const int r0 = tid >> 3, k0b = tid & 7;
  const int r1 = (tid + 256) >> 3, k1b = tid & 7;
  const f16* ks0 = Kp + ((size_t)b * 512 + r0) * NC + hh * 64 + ((k0b ^ (r0 & 7)) * 8);
  const f16* ks1 = Kp + ((size_t)b * 512 + r1) * NC + hh * 64 + ((k1b ^ (r1 & 7)) * 8);
  const f16* vs0 = Vt + ((size_t)b * NC + hh * 64 + r0) * 512 + ((k0b ^ (r0 & 7)) * 8);
  const f16* vs1 = Vt + ((size_t)b * NC + hh * 64 + r1) * 512 + ((k1b ^ (r1 & 7)) * 8);
  gll16(ks0, (char*)&Ks[0][0] + tid * 16);
  gll16(ks1, (char*)&Ks[0][0] + (tid + 256) * 16);
  gll16(vs0, (char*)&Vs[0][0] + tid * 16);
  gll16(vs1, (char*)&Vs[0][0] + (tid + 256) * 16);

  int buf = 0;
  for (int ch = 0; ch < 8; ++ch) {
    __syncthreads();
    if (ch < 7) {
      gll16(ks0 + (size_t)(ch + 1) * 64 * NC, (char*)&Ks[buf ^ 1][0] + tid * 16);
      gll16(ks1 + (size_t)(ch + 1) * 64 * NC, (char*)&Ks[buf ^ 1][0] + (tid + 256) * 16);
      gll16(vs0 + (ch + 1) * 64, (char*)&Vs[buf ^ 1][0] + tid * 16);
      gll16(vs1 + (ch + 1) * 64, (char*)&Vs[buf ^ 1][0] + (tid + 256) * 16);
    }
    const char* kb = (const char*)&Ks[buf][0];
    const char* vb = (const char*)&Vs[buf][0];
#pragma unroll
    for (int half = 0; half < 2; ++half) {
      f32x16 st = {};
#pragma unroll
      for (int ks = 0; ks < 4; ++ks) {
        const int bo = ((2 * ks + h) ^ (c & 7)) * 16;
        const f16x8 kf = *(const f16x8*)(kb + (32 * half + c) * 128 + bo);
        st = MFMA32(kf, qf[ks], st);
      }
      u32 pk[8];
      float ps0 = 0.f, ps1 = 0.f;
#pragma unroll
      for (int t = 0; t < 8; ++t) {
        const float a0 = exp2f(st[2 * t]);
        const float a1 = exp2f(st[2 * t + 1]);
        ps0 += a0; ps1 += a1;
        pk[t] = pkf16(a0, a1);
      }
      l_run += ps0 + ps1;
#pragma unroll
      for (int ss = 0; ss < 2; ++ss) {
        const int s = half * 2 + ss, tb = ss * 4;
        const u32 xs = h ? pk[tb + 0] : pk[tb + 2];
        const u32 ys = h ? pk[tb + 1] : pk[tb + 3];
        const u32 rx = __shfl_xor(xs, 32);
        const u32 ry = __shfl_xor(ys, 32);
        u32x4 fi;
        fi[0] = h ? rx : pk[tb + 0];
        fi[1] = h ? ry : pk[tb + 1];
        fi[2] = h ? pk[tb + 2] : rx;
        fi[3] = h ? pk[tb + 3] : ry;
        const f16x8 pfrag = __builtin_bit_cast(f16x8, fi);
        const int bo = ((2 * s + h) ^ (c & 7)) * 16;
        const f16x8 v0 = *(const f16x8*)(vb + c * 128 + bo);
        const f16x8 v1 = *(const f16x8*)(vb + (32 + c) * 128 + bo);
        oa0 = MFMA32(v0, pfrag, oa0);
        oa1 = MFMA32(v1, pfrag, oa1);
      }
    }
    buf ^= 1;
  }
  const float ltot = l_run + __shfl_xor(l_run, 32);
  const float linv = 1.0f / ltot;
  f16* orow = O + qrow * NC + hh * 64;
#pragma unroll
  for (int dt = 0; dt < 2; ++dt) {
#pragma unroll
    for (int qd = 0; qd < 4; ++qd) {
      const float v0 = (dt ? oa1[4 * qd + 0] : oa0[4 * qd + 0]) * linv;
      const float v1 = (dt ? oa1[4 * qd + 1] : oa0[4 * qd + 1]) * linv;
      const float v2 = (dt ? oa1[4 * qd + 2] : oa0[4 * qd + 2]) * linv;
      const float v3 = (dt ? oa1[4 * qd + 3] : oa0[4 * qd + 3]) * linv;
      uint2 pr; pr.x = pkf16(v0, v1); pr.y = pkf16(v2, v3);
      *(uint2*)(orow + dt * 32 + 8 * qd + 4 * h) = pr;
    }
  }
}

// ---------------- launch ----------------
extern "C" void kernel_launch(void* const* d_in, const int* in_sizes, int n_in,
                              void* d_out, int out_size, void* d_ws, size_t ws_size,
                              hipStream_t stream) {
  const float* x   = (const float*)d_in[0];
  const float* cqw = (const float*)d_in[1];
  const float* ckw = (const float*)d_in[2];
  const float* cvw = (const float*)d_in[3];
  const float* bqg = (const float*)d_in[4],  *bqb = (const float*)d_in[5];
  const float* bqm = (const float*)d_in[6],  *bqv = (const float*)d_in[7];
  const float* bkg = (const float*)d_in[8],  *bkb = (const float*)d_in[9];
  const float* bkm = (const float*)d_in[10], *bkv = (const float*)d_in[11];
  const float* bvg = (const float*)d_in[12], *bvb = (const float*)d_in[13];
  const float* bvm = (const float*)d_in[14], *bvv = (const float*)d_in[15];
  const float* wq = (const float*)d_in[16];
  const float* wk = (const float*)d_in[17];
  const float* wv = (const float*)d_in[18];
  const float* pw = (const float*)d_in[19];
  const float* pb = (const float*)d_in[20];

  f16* q_tok = (f16*)d_out;                              // lo half (25 MB)
  f16* Qp    = (f16*)((char*)d_out + 25165824);          // hi half (25 MB)

  char* ws = (char*)d_ws;
  f16* wq_h  = (f16*)(ws + 0);
  f16* wk_h  = (f16*)(ws + 294912);
  f16* wv_h  = (f16*)(ws + 589824);
  f16* pw_h  = (f16*)(ws + 884736);
  f16* k_tok = (f16*)(ws + 1179648);
  f16* v_tok = (f16*)(ws + 4325376);
  f16* Kp    = (f16*)(ws + 7471104);
  f16* Vt    = (f16*)(ws + 10616832);
  f16* Oi    = (f16*)(ws + 13762560);
  float* wqT = (float*)(ws + 38928384);
  float* wkT = (float*)(ws + 38969856);
  float* wvT = (float*)(ws + 39011328);   // ws total 39,052,800 B

  const float scq = 0.051031036307982884f * 1.4426950408889634f; // 384^-0.5 * log2(e)
  cvt_w<<<dim3(576), dim3(256), 0, stream>>>(wq, wk, wv, pw, wq_h, wk_h, wv_h, pw_h,
                                             147456, scq);
  cvt_wt<<<dim3(27), dim3(384), 0, stream>>>(cqw, ckw, cvw, wqT, wkT, wvT);
  conv_q<<<dim3(192, 8, 4), dim3(128), 0, stream>>>(
      x, wqT, bqg, bqb, bqm, bqv, q_tok);
  conv_kv<<<dim3(192, 8, 2), dim3(128), 0, stream>>>(
      x, wkT, wvT, bkg, bkb, bkm, bkv, bvg, bvb, bvm, bvv, k_tok, v_tok);
  gemm_bt<0><<<dim3(3, 256), dim3(256), 0, stream>>>(q_tok, wq_h, Qp, nullptr);
  gemm_bt<0><<<dim3(3, 32),  dim3(256), 0, stream>>>(k_tok, wk_h, Kp, nullptr);
  gemm_bt<1><<<dim3(3, 32),  dim3(256), 0, stream>>>(v_tok, wv_h, Vt, nullptr);
  attn<<<dim3(32, 6, 8), dim3(256), 0, stream>>>(Qp, Kp, Vt, Oi);
  gemm_bt<2><<<dim3(3, 256), dim3(256), 0, stream>>>(Oi, pw_h, d_out, pb);
}

// Round 16
// 147.491 us; speedup vs baseline: 1.3029x; 1.3029x over previous
//
#include <hip/hip_runtime.h>
#include <hip/hip_bf16.h>
#include <stdint.h>

// Round 16: revert R15 fission (regressed; double x-read). conv = R14 fused
// 2-wave version (67 us). attn: exp2f -> __builtin_amdgcn_exp2f (v_exp_f32,
// 1 inst vs ~15-inst libcall) — R15 profile showed 52% VALUBusy, ~7x my op
// count; the libcall is the only candidate. GEMMs frozen.

typedef _Float16 f16;
typedef _Float16 f16x8 __attribute__((ext_vector_type(8)));
typedef float f32x4 __attribute__((ext_vector_type(4)));
typedef float f32x16 __attribute__((ext_vector_type(16)));
typedef uint32_t u32;
typedef uint32_t u32x4 __attribute__((ext_vector_type(4)));

#define NC 384
#define MFMA16(A_,B_,C_) __builtin_amdgcn_mfma_f32_16x16x32_f16((A_),(B_),(C_),0,0,0)
#define MFMA32(A_,B_,C_) __builtin_amdgcn_mfma_f32_32x32x16_f16((A_),(B_),(C_),0,0,0)

__device__ __forceinline__ void gll16(const void* g, void* l) {
  __builtin_amdgcn_global_load_lds(
      (__attribute__((address_space(1))) void*)g,
      (__attribute__((address_space(3))) void*)l, 16, 0, 0);
}

__device__ __forceinline__ u32 pkf16(float lo, float hi) {
  return __builtin_bit_cast(u32, __builtin_amdgcn_cvt_pkrtz(lo, hi));
}

// ---------------- weight fp32 -> f16 convert (scq folded into wq) ----------------
__global__ __launch_bounds__(256) void cvt_w(
    const float* __restrict__ s0, const float* __restrict__ s1,
    const float* __restrict__ s2, const float* __restrict__ s3,
    f16* __restrict__ d0, f16* __restrict__ d1,
    f16* __restrict__ d2, f16* __restrict__ d3, int n, float scq)
{
  int i = blockIdx.x * 256 + threadIdx.x;
  if (i < n) {
    d0[i] = (f16)(s0[i] * scq);
    d1[i] = (f16)s1[i]; d2[i] = (f16)s2[i]; d3[i] = (f16)s3[i];
  }
}

// ---------------- conv-weight transpose [384][27] -> [27][384] ----------------
__global__ __launch_bounds__(384) void cvt_wt(
    const float* __restrict__ wq, const float* __restrict__ wk, const float* __restrict__ wv,
    float* __restrict__ qT, float* __restrict__ kT, float* __restrict__ vT)
{
  const int c = threadIdx.x;
  const int t = blockIdx.x;
  qT[t * 384 + c] = wq[c * 27 + t];
  kT[t * 384 + c] = wk[c * 27 + t];
  vT[t * 384 + c] = wv[c * 27 + t];
}

// ---------------- fused depthwise conv3d + BN, 128-thread (2-wave) blocks ----------------
// grid (64 hw-tiles x 3 c-thirds, 8 b, 2 z-chunks); c = cthird*128 + tid.
__global__ __launch_bounds__(128) void conv_fused(
    const float* __restrict__ x,
    const float* __restrict__ wqT, const float* __restrict__ wkT, const float* __restrict__ wvT,
    const float* __restrict__ bqg, const float* __restrict__ bqb,
    const float* __restrict__ bqm, const float* __restrict__ bqv,
    const float* __restrict__ bkg, const float* __restrict__ bkb,
    const float* __restrict__ bkm, const float* __restrict__ bkv,
    const float* __restrict__ bvg, const float* __restrict__ bvb,
    const float* __restrict__ bvm, const float* __restrict__ bvv,
    f16* __restrict__ qout, f16* __restrict__ kout, f16* __restrict__ vout)
{
  const int tile = blockIdx.x / 3, cthird = blockIdx.x % 3;
  const int c = cthird * 128 + threadIdx.x;
  const int th = tile >> 3, tw = tile & 7;
  const int b = blockIdx.y;
  const int z0 = blockIdx.z * 8;
  const int h0 = th * 2, w0 = tw * 2;

  float wqr[27], wkr[27], wvr[27];
#pragma unroll
  for (int t = 0; t < 27; ++t) {
    wqr[t] = wqT[t * 384 + c];
    wkr[t] = wkT[t * 384 + c];
    wvr[t] = wvT[t * 384 + c];
  }
  float invq = bqg[c] * rsqrtf(bqv[c] + 1e-5f), betq = bqb[c] - bqm[c] * invq;
  float invk = bkg[c] * rsqrtf(bkv[c] + 1e-5f), betk = bkb[c] - bkm[c] * invk;
  float invv = bvg[c] * rsqrtf(bvv[c] + 1e-5f), betv = bvb[c] - bvm[c] * invv;

  bool hok[4], wok[4];
#pragma unroll
  for (int a = 0; a < 4; ++a) {
    hok[a] = (unsigned)(h0 - 1 + a) < 16u;
    wok[a] = (unsigned)(w0 - 1 + a) < 16u;
  }
  const float* xb = x + (size_t)b * 4096 * NC + c;

  float win[3][4][4];
  auto ldplane = [&](int s, int iz) {
    const bool zok = (unsigned)iz < 16u;
#pragma unroll
    for (int a = 0; a < 4; ++a)
#pragma unroll
      for (int e = 0; e < 4; ++e) {
        float v = 0.f;
        if (zok && hok[a] && wok[e])
          v = xb[(size_t)((h0 - 1 + a) * 256 + (w0 - 1 + e) * 16 + iz) * NC];
        win[s][a][e] = v;
      }
  };
  ldplane(2, z0 - 1);
  ldplane(0, z0);

#pragma unroll
  for (int zr = 0; zr < 8; ++zr) {
    const int z = z0 + zr;
    const int snew = (zr + 1) % 3;
    ldplane(snew, z + 1);
    float aq00 = 0.f, aq01 = 0.f, aq10 = 0.f, aq11 = 0.f;
    float ak = 0.f, av = 0.f;
#pragma unroll
    for (int p = 0; p < 3; ++p) {
      const int s = (zr - 1 + p + 3) % 3;
#pragma unroll
      for (int a = 0; a < 3; ++a)
#pragma unroll
        for (int e = 0; e < 3; ++e) {
          const float w00 = win[s][a][e],     w01 = win[s][a][e + 1];
          const float w10 = win[s][a + 1][e], w11 = win[s][a + 1][e + 1];
          const float cq = wqr[a * 9 + e * 3 + p];
          aq00 += w00 * cq; aq01 += w01 * cq;
          aq10 += w10 * cq; aq11 += w11 * cq;
          if ((zr & 1) == 0) {
            ak += w00 * wkr[a * 9 + e * 3 + p];
            av += w00 * wvr[a * 9 + e * 3 + p];
          }
        }
    }
    const size_t qb = (size_t)b * 4096;
    qout[(qb + (h0 + 0) * 256 + (w0 + 0) * 16 + z) * NC + c] = (f16)(aq00 * invq + betq);
    qout[(qb + (h0 + 0) * 256 + (w0 + 1) * 16 + z) * NC + c] = (f16)(aq01 * invq + betq);
    qout[(qb + (h0 + 1) * 256 + (w0 + 0) * 16 + z) * NC + c] = (f16)(aq10 * invq + betq);
    qout[(qb + (h0 + 1) * 256 + (w0 + 1) * 16 + z) * NC + c] = (f16)(aq11 * invq + betq);
    if ((zr & 1) == 0) {
      const size_t t = (size_t)b * 512 + (th * 8 + tw) * 8 + (z >> 1);
      kout[t * NC + c] = (f16)(ak * invk + betk);
      vout[t * NC + c] = (f16)(av * invv + betv);
    }
  }
}

// ---------------- GEMM (R8 version): gll16 staging + XOR-swizzled LDS ----------------
template<int MODE>
__global__ __launch_bounds__(256) void gemm_bt(
    const f16* __restrict__ A, const f16* __restrict__ Bw,
    void* __restrict__ Cout, const float* __restrict__ bias)
{
  __shared__ f16 As[128 * 64];
  __shared__ f16 Bs[128 * 64];
  const int tid = threadIdx.x;
  const int w = tid >> 6, lane = tid & 63;
  const int g = lane >> 4, q = lane & 15;
  const int wr = w >> 1, wc = w & 1;
  const size_t brow = (size_t)blockIdx.y * 128;
  const int bcol = blockIdx.x * 128;
  const int srow = lane >> 3;
  const int sbb  = (lane & 7) ^ (srow & 7);
  f32x4 acc[4][4] = {};
  for (int kt = 0; kt < 6; ++kt) {
    const int k0 = kt * 64;
#pragma unroll
    for (int j = 0; j < 4; ++j) {
      const int s = w * 4 + j;
      gll16(A  + (brow + (size_t)(s * 8 + srow)) * NC + k0 + sbb * 8, (char*)As + s * 1024);
      gll16(Bw + (size_t)(bcol + s * 8 + srow) * NC + k0 + sbb * 8, (char*)Bs + s * 1024);
    }
    __syncthreads();
#pragma unroll
    for (int ks = 0; ks < 2; ++ks) {
      f16x8 af[4], bfr[4];
      const int bb = ((g + 4 * ks) ^ (q & 7)) * 16;
#pragma unroll
      for (int m = 0; m < 4; ++m) {
        af[m]  = *(const f16x8*)((const char*)As + (wr * 64 + m * 16 + q) * 128 + bb);
        bfr[m] = *(const f16x8*)((const char*)Bs + (wc * 64 + m * 16 + q) * 128 + bb);
      }
#pragma unroll
      for (int m = 0; m < 4; ++m)
#pragma unroll
        for (int n = 0; n < 4; ++n)
          acc[m][n] = MFMA16(af[m], bfr[n], acc[m][n]);
    }
    __syncthreads();
  }
  float bvals[4];
  if (MODE == 2) {
#pragma unroll
    for (int n = 0; n < 4; ++n) bvals[n] = bias[bcol + wc * 64 + n * 16 + q];
  }
#pragma unroll
  for (int m = 0; m < 4; ++m) {
#pragma unroll
    for (int n = 0; n < 4; ++n) {
#pragma unroll
      for (int r = 0; r < 4; ++r) {
        const size_t row = brow + wr * 64 + m * 16 + 4 * g + r;
        const int col = bcol + wc * 64 + n * 16 + q;
        const float v = acc[m][n][r];
        if (MODE == 0) {
          ((f16*)Cout)[row * NC + col] = (f16)v;
        } else if (MODE == 1) {
          const size_t bi = row >> 9, t = row & 511;
          ((f16*)Cout)[(bi * NC + col) * 512 + t] = (f16)v;
        } else {
          ((float*)Cout)[row * NC + col] = v + bvals[n];
        }
      }
    }
  }
}

// ---------------- flash attention: per-half pipeline, v_exp_f32 ----------------
// grid (32 qtiles, 6 heads, 8 b); 256 thr = 4 waves x 32 q-rows. KVBLK=64, dbuf.
__global__ __launch_bounds__(256) void attn(
    const f16* __restrict__ Qp, const f16* __restrict__ Kp,
    const f16* __restrict__ Vt, f16* __restrict__ O)
{
  __shared__ f16 Ks[2][64 * 64];
  __shared__ f16 Vs[2][64 * 64];
  const int tid = threadIdx.x;
  const int w = tid >> 6, lane = tid & 63;
  const int c = lane & 31, h = lane >> 5;
  const int qt = blockIdx.x, hh = blockIdx.y, b = blockIdx.z;
  const size_t qrow = (size_t)b * 4096 + qt * 128 + w * 32 + c;

  f16x8 qf[4];
#pragma unroll
  for (int ks = 0; ks < 4; ++ks)
    qf[ks] = *(const f16x8*)(Qp + qrow * NC + hh * 64 + ks * 16 + 8 * h);

  f32x16 oa0 = {}, oa1 = {};
  float l_run = 0.f;

  const int r0 = tid >> 3, k0b = tid & 7;
  const int r1 = (tid + 256) >> 3, k1b = tid & 7;
  const f16* ks0 = Kp + ((size_t)b * 512 + r0) * NC + hh * 64 + ((k0b ^ (r0 & 7)) * 8);
  const f16* ks1 = Kp + ((size_t)b * 512 + r1) * NC + hh * 64 + ((k1b ^ (r1 & 7)) * 8);
  const f16* vs0 = Vt + ((size_t)b * NC + hh * 64 + r0) * 512 + ((k0b ^ (r0 & 7)) * 8);
  const f16* vs1 = Vt + ((size_t)b * NC + hh * 64 + r1) * 512 + ((k1b ^ (r1 & 7)) * 8);
  gll16(ks0, (char*)&Ks[0][0] + tid * 16);
  gll16(ks1, (char*)&Ks[0][0] + (tid + 256) * 16);
  gll16(vs0, (char*)&Vs[0][0] + tid * 16);
  gll16(vs1, (char*)&Vs[0][0] + (tid + 256) * 16);

  int buf = 0;
  for (int ch = 0; ch < 8; ++ch) {
    __syncthreads();
    if (ch < 7) {
      gll16(ks0 + (size_t)(ch + 1) * 64 * NC, (char*)&Ks[buf ^ 1][0] + tid * 16);
      gll16(ks1 + (size_t)(ch + 1) * 64 * NC, (char*)&Ks[buf ^ 1][0] + (tid + 256) * 16);
      gll16(vs0 + (ch + 1) * 64, (char*)&Vs[buf ^ 1][0] + tid * 16);
      gll16(vs1 + (ch + 1) * 64, (char*)&Vs[buf ^ 1][0] + (tid + 256) * 16);
    }
    const char* kb = (const char*)&Ks[buf][0];
    const char* vb = (const char*)&Vs[buf][0];
#pragma unroll
    for (int half = 0; half < 2; ++half) {
      f32x16 st = {};
#pragma unroll
      for (int ks = 0; ks < 4; ++ks) {
        const int bo = ((2 * ks + h) ^ (c & 7)) * 16;
        const f16x8 kf = *(const f16x8*)(kb + (32 * half + c) * 128 + bo);
        st = MFMA32(kf, qf[ks], st);
      }
      u32 pk[8];
      float ps0 = 0.f, ps1 = 0.f;
#pragma unroll
      for (int t = 0; t < 8; ++t) {
        const float a0 = __builtin_amdgcn_exp2f(st[2 * t]);      // v_exp_f32
        const float a1 = __builtin_amdgcn_exp2f(st[2 * t + 1]);
        ps0 += a0; ps1 += a1;
        pk[t] = pkf16(a0, a1);
      }
      l_run += ps0 + ps1;
#pragma unroll
      for (int ss = 0; ss < 2; ++ss) {
        const int s = half * 2 + ss, tb = ss * 4;
        const u32 xs = h ? pk[tb + 0] : pk[tb + 2];
        const u32 ys = h ? pk[tb + 1] : pk[tb + 3];
        const u32 rx = __shfl_xor(xs, 32);
        const u32 ry = __shfl_xor(ys, 32);
        u32x4 fi;
        fi[0] = h ? rx : pk[tb + 0];
        fi[1] = h ? ry : pk[tb + 1];
        fi[2] = h ? pk[tb + 2] : rx;
        fi[3] = h ? pk[tb + 3] : ry;
        const f16x8 pfrag = __builtin_bit_cast(f16x8, fi);
        const int bo = ((2 * s + h) ^ (c & 7)) * 16;
        const f16x8 v0 = *(const f16x8*)(vb + c * 128 + bo);
        const f16x8 v1 = *(const f16x8*)(vb + (32 + c) * 128 + bo);
        oa0 = MFMA32(v0, pfrag, oa0);
        oa1 = MFMA32(v1, pfrag, oa1);
      }
    }
    buf ^= 1;
  }
  const float ltot = l_run + __shfl_xor(l_run, 32);
  const float linv = 1.0f / ltot;
  f16* orow = O + qrow * NC + hh * 64;
#pragma unroll
  for (int dt = 0; dt < 2; ++dt) {
#pragma unroll
    for (int qd = 0; qd < 4; ++qd) {
      const float v0 = (dt ? oa1[4 * qd + 0] : oa0[4 * qd + 0]) * linv;
      const float v1 = (dt ? oa1[4 * qd + 1] : oa0[4 * qd + 1]) * linv;
      const float v2 = (dt ? oa1[4 * qd + 2] : oa0[4 * qd + 2]) * linv;
      const float v3 = (dt ? oa1[4 * qd + 3] : oa0[4 * qd + 3]) * linv;
      uint2 pr; pr.x = pkf16(v0, v1); pr.y = pkf16(v2, v3);
      *(uint2*)(orow + dt * 32 + 8 * qd + 4 * h) = pr;
    }
  }
}

// ---------------- launch ----------------
extern "C" void kernel_launch(void* const* d_in, const int* in_sizes, int n_in,
                              void* d_out, int out_size, void* d_ws, size_t ws_size,
                              hipStream_t stream) {
  const float* x   = (const float*)d_in[0];
  const float* cqw = (const float*)d_in[1];
  const float* ckw = (const float*)d_in[2];
  const float* cvw = (const float*)d_in[3];
  const float* bqg = (const float*)d_in[4],  *bqb = (const float*)d_in[5];
  const float* bqm = (const float*)d_in[6],  *bqv = (const float*)d_in[7];
  const float* bkg = (const float*)d_in[8],  *bkb = (const float*)d_in[9];
  const float* bkm = (const float*)d_in[10], *bkv = (const float*)d_in[11];
  const float* bvg = (const float*)d_in[12], *bvb = (const float*)d_in[13];
  const float* bvm = (const float*)d_in[14], *bvv = (const float*)d_in[15];
  const float* wq = (const float*)d_in[16];
  const float* wk = (const float*)d_in[17];
  const float* wv = (const float*)d_in[18];
  const float* pw = (const float*)d_in[19];
  const float* pb = (const float*)d_in[20];

  f16* q_tok = (f16*)d_out;                              // lo half (25 MB)
  f16* Qp    = (f16*)((char*)d_out + 25165824);          // hi half (25 MB)

  char* ws = (char*)d_ws;
  f16* wq_h  = (f16*)(ws + 0);
  f16* wk_h  = (f16*)(ws + 294912);
  f16* wv_h  = (f16*)(ws + 589824);
  f16* pw_h  = (f16*)(ws + 884736);
  f16* k_tok = (f16*)(ws + 1179648);
  f16* v_tok = (f16*)(ws + 4325376);
  f16* Kp    = (f16*)(ws + 7471104);
  f16* Vt    = (f16*)(ws + 10616832);
  f16* Oi    = (f16*)(ws + 13762560);
  float* wqT = (float*)(ws + 38928384);
  float* wkT = (float*)(ws + 38969856);
  float* wvT = (float*)(ws + 39011328);   // ws total 39,052,800 B

  const float scq = 0.051031036307982884f * 1.4426950408889634f; // 384^-0.5 * log2(e)
  cvt_w<<<dim3(576), dim3(256), 0, stream>>>(wq, wk, wv, pw, wq_h, wk_h, wv_h, pw_h,
                                             147456, scq);
  cvt_wt<<<dim3(27), dim3(384), 0, stream>>>(cqw, ckw, cvw, wqT, wkT, wvT);
  conv_fused<<<dim3(192, 8, 2), dim3(128), 0, stream>>>(
      x, wqT, wkT, wvT,
      bqg, bqb, bqm, bqv, bkg, bkb, bkm, bkv, bvg, bvb, bvm, bvv,
      q_tok, k_tok, v_tok);
  gemm_bt<0><<<dim3(3, 256), dim3(256), 0, stream>>>(q_tok, wq_h, Qp, nullptr);
  gemm_bt<0><<<dim3(3, 32),  dim3(256), 0, stream>>>(k_tok, wk_h, Kp, nullptr);
  gemm_bt<1><<<dim3(3, 32),  dim3(256), 0, stream>>>(v_tok, wv_h, Vt, nullptr);
  attn<<<dim3(32, 6, 8), dim3(256), 0, stream>>>(Qp, Kp, Vt, Oi);
  gemm_bt<2><<<dim3(3, 256), dim3(256), 0, stream>>>(Oi, pw_h, d_out, pb);
}

// Round 17
// 146.141 us; speedup vs baseline: 1.3149x; 1.0092x over previous
//
#include <hip/hip_runtime.h>
#include <hip/hip_bf16.h>
#include <stdint.h>

// Round 17: conv prefetch-distance-2 (4-slot plane ring) — R16 diagnosis: with
// 3 slots, compute(z) consumes the plane issued in the SAME iteration => 8
// serial HBM latencies/block. Now plane z+2 is issued at iter z; compute uses
// planes loaded >=1 iter earlier. BN inv folded into weights (prep kernel).
// attn (R16, v_exp_f32) / GEMMs frozen.

typedef _Float16 f16;
typedef _Float16 f16x8 __attribute__((ext_vector_type(8)));
typedef float f32x4 __attribute__((ext_vector_type(4)));
typedef float f32x16 __attribute__((ext_vector_type(16)));
typedef uint32_t u32;
typedef uint32_t u32x4 __attribute__((ext_vector_type(4)));

#define NC 384
#define MFMA16(A_,B_,C_) __builtin_amdgcn_mfma_f32_16x16x32_f16((A_),(B_),(C_),0,0,0)
#define MFMA32(A_,B_,C_) __builtin_amdgcn_mfma_f32_32x32x16_f16((A_),(B_),(C_),0,0,0)

__device__ __forceinline__ void gll16(const void* g, void* l) {
  __builtin_amdgcn_global_load_lds(
      (__attribute__((address_space(1))) void*)g,
      (__attribute__((address_space(3))) void*)l, 16, 0, 0);
}

__device__ __forceinline__ u32 pkf16(float lo, float hi) {
  return __builtin_bit_cast(u32, __builtin_amdgcn_cvt_pkrtz(lo, hi));
}

// ---------------- weight fp32 -> f16 convert (scq folded into wq) ----------------
__global__ __launch_bounds__(256) void cvt_w(
    const float* __restrict__ s0, const float* __restrict__ s1,
    const float* __restrict__ s2, const float* __restrict__ s3,
    f16* __restrict__ d0, f16* __restrict__ d1,
    f16* __restrict__ d2, f16* __restrict__ d3, int n, float scq)
{
  int i = blockIdx.x * 256 + threadIdx.x;
  if (i < n) {
    d0[i] = (f16)(s0[i] * scq);
    d1[i] = (f16)s1[i]; d2[i] = (f16)s2[i]; d3[i] = (f16)s3[i];
  }
}

// ---------------- conv-weight transpose + BN fold: w' = w*inv, beta arrays ----------------
__global__ __launch_bounds__(384) void cvt_wt(
    const float* __restrict__ wq, const float* __restrict__ wk, const float* __restrict__ wv,
    const float* __restrict__ bqg, const float* __restrict__ bqb,
    const float* __restrict__ bqm, const float* __restrict__ bqv,
    const float* __restrict__ bkg, const float* __restrict__ bkb,
    const float* __restrict__ bkm, const float* __restrict__ bkv,
    const float* __restrict__ bvg, const float* __restrict__ bvb,
    const float* __restrict__ bvm, const float* __restrict__ bvv,
    float* __restrict__ qT, float* __restrict__ kT, float* __restrict__ vT,
    float* __restrict__ betq, float* __restrict__ betk, float* __restrict__ betv)
{
  const int c = threadIdx.x;
  const int t = blockIdx.x;   // 0..26
  const float invq = bqg[c] * rsqrtf(bqv[c] + 1e-5f);
  const float invk = bkg[c] * rsqrtf(bkv[c] + 1e-5f);
  const float invv = bvg[c] * rsqrtf(bvv[c] + 1e-5f);
  qT[t * 384 + c] = wq[c * 27 + t] * invq;
  kT[t * 384 + c] = wk[c * 27 + t] * invk;
  vT[t * 384 + c] = wv[c * 27 + t] * invv;
  if (t == 0) {
    betq[c] = bqb[c] - bqm[c] * invq;
    betk[c] = bkb[c] - bkm[c] * invk;
    betv[c] = bvb[c] - bvm[c] * invv;
  }
}

// ---------------- fused depthwise conv3d + BN, 4-slot ring / prefetch-2 ----------------
// 128 thr (2 waves); grid (64 tiles x 3 c-thirds, 8 b, 2 z-chunks).
__global__ __launch_bounds__(128, 3) void conv_fused(
    const float* __restrict__ x,
    const float* __restrict__ wqT, const float* __restrict__ wkT, const float* __restrict__ wvT,
    const float* __restrict__ betq_, const float* __restrict__ betk_,
    const float* __restrict__ betv_,
    f16* __restrict__ qout, f16* __restrict__ kout, f16* __restrict__ vout)
{
  const int tile = blockIdx.x / 3, cthird = blockIdx.x % 3;
  const int c = cthird * 128 + threadIdx.x;
  const int th = tile >> 3, tw = tile & 7;
  const int b = blockIdx.y;
  const int z0 = blockIdx.z * 8;
  const int h0 = th * 2, w0 = tw * 2;

  float wqr[27], wkr[27], wvr[27];
#pragma unroll
  for (int t = 0; t < 27; ++t) {
    wqr[t] = wqT[t * 384 + c];   // pre-scaled by BN inv
    wkr[t] = wkT[t * 384 + c];
    wvr[t] = wvT[t * 384 + c];
  }
  const float betq = betq_[c], betk = betk_[c], betv = betv_[c];

  bool hok[4], wok[4];
#pragma unroll
  for (int a = 0; a < 4; ++a) {
    hok[a] = (unsigned)(h0 - 1 + a) < 16u;
    wok[a] = (unsigned)(w0 - 1 + a) < 16u;
  }
  const float* xb = x + (size_t)b * 4096 * NC + c;

  float win[4][4][4];   // 4-slot ring: plane (z0-1+p) -> slot p&3
  auto ldplane = [&](int s, int iz) {   // s compile-time after unroll
    const bool zok = (unsigned)iz < 16u;
#pragma unroll
    for (int a = 0; a < 4; ++a)
#pragma unroll
      for (int e = 0; e < 4; ++e) {
        float v = 0.f;
        if (zok && hok[a] && wok[e])
          v = xb[(size_t)((h0 - 1 + a) * 256 + (w0 - 1 + e) * 16 + iz) * NC];
        win[s][a][e] = v;
      }
  };
  ldplane(0, z0 - 1);
  ldplane(1, z0);
  ldplane(2, z0 + 1);

#pragma unroll
  for (int zr = 0; zr < 8; ++zr) {
    const int z = z0 + zr;
    ldplane((zr + 3) & 3, z + 2);   // prefetch distance 2: plane index zr+3
    float aq00 = 0.f, aq01 = 0.f, aq10 = 0.f, aq11 = 0.f;
    float ak = 0.f, av = 0.f;
#pragma unroll
    for (int p = 0; p < 3; ++p) {
      const int s = (zr + p) & 3;   // planes z-1..z+1, loaded >=1 iter ago
#pragma unroll
      for (int a = 0; a < 3; ++a)
#pragma unroll
        for (int e = 0; e < 3; ++e) {
          const float w00 = win[s][a][e],     w01 = win[s][a][e + 1];
          const float w10 = win[s][a + 1][e], w11 = win[s][a + 1][e + 1];
          const float cq = wqr[a * 9 + e * 3 + p];
          aq00 += w00 * cq; aq01 += w01 * cq;
          aq10 += w10 * cq; aq11 += w11 * cq;
          if ((zr & 1) == 0) {
            ak += w00 * wkr[a * 9 + e * 3 + p];
            av += w00 * wvr[a * 9 + e * 3 + p];
          }
        }
    }
    const size_t qb = (size_t)b * 4096;
    qout[(qb + (h0 + 0) * 256 + (w0 + 0) * 16 + z) * NC + c] = (f16)(aq00 + betq);
    qout[(qb + (h0 + 0) * 256 + (w0 + 1) * 16 + z) * NC + c] = (f16)(aq01 + betq);
    qout[(qb + (h0 + 1) * 256 + (w0 + 0) * 16 + z) * NC + c] = (f16)(aq10 + betq);
    qout[(qb + (h0 + 1) * 256 + (w0 + 1) * 16 + z) * NC + c] = (f16)(aq11 + betq);
    if ((zr & 1) == 0) {
      const size_t t = (size_t)b * 512 + (th * 8 + tw) * 8 + (z >> 1);
      kout[t * NC + c] = (f16)(ak + betk);
      vout[t * NC + c] = (f16)(av + betv);
    }
  }
}

// ---------------- GEMM (R8 version): gll16 staging + XOR-swizzled LDS ----------------
template<int MODE>
__global__ __launch_bounds__(256) void gemm_bt(
    const f16* __restrict__ A, const f16* __restrict__ Bw,
    void* __restrict__ Cout, const float* __restrict__ bias)
{
  __shared__ f16 As[128 * 64];
  __shared__ f16 Bs[128 * 64];
  const int tid = threadIdx.x;
  const int w = tid >> 6, lane = tid & 63;
  const int g = lane >> 4, q = lane & 15;
  const int wr = w >> 1, wc = w & 1;
  const size_t brow = (size_t)blockIdx.y * 128;
  const int bcol = blockIdx.x * 128;
  const int srow = lane >> 3;
  const int sbb  = (lane & 7) ^ (srow & 7);
  f32x4 acc[4][4] = {};
  for (int kt = 0; kt < 6; ++kt) {
    const int k0 = kt * 64;
#pragma unroll
    for (int j = 0; j < 4; ++j) {
      const int s = w * 4 + j;
      gll16(A  + (brow + (size_t)(s * 8 + srow)) * NC + k0 + sbb * 8, (char*)As + s * 1024);
      gll16(Bw + (size_t)(bcol + s * 8 + srow) * NC + k0 + sbb * 8, (char*)Bs + s * 1024);
    }
    __syncthreads();
#pragma unroll
    for (int ks = 0; ks < 2; ++ks) {
      f16x8 af[4], bfr[4];
      const int bb = ((g + 4 * ks) ^ (q & 7)) * 16;
#pragma unroll
      for (int m = 0; m < 4; ++m) {
        af[m]  = *(const f16x8*)((const char*)As + (wr * 64 + m * 16 + q) * 128 + bb);
        bfr[m] = *(const f16x8*)((const char*)Bs + (wc * 64 + m * 16 + q) * 128 + bb);
      }
#pragma unroll
      for (int m = 0; m < 4; ++m)
#pragma unroll
        for (int n = 0; n < 4; ++n)
          acc[m][n] = MFMA16(af[m], bfr[n], acc[m][n]);
    }
    __syncthreads();
  }
  float bvals[4];
  if (MODE == 2) {
#pragma unroll
    for (int n = 0; n < 4; ++n) bvals[n] = bias[bcol + wc * 64 + n * 16 + q];
  }
#pragma unroll
  for (int m = 0; m < 4; ++m) {
#pragma unroll
    for (int n = 0; n < 4; ++n) {
#pragma unroll
      for (int r = 0; r < 4; ++r) {
        const size_t row = brow + wr * 64 + m * 16 + 4 * g + r;
        const int col = bcol + wc * 64 + n * 16 + q;
        const float v = acc[m][n][r];
        if (MODE == 0) {
          ((f16*)Cout)[row * NC + col] = (f16)v;
        } else if (MODE == 1) {
          const size_t bi = row >> 9, t = row & 511;
          ((f16*)Cout)[(bi * NC + col) * 512 + t] = (f16)v;
        } else {
          ((float*)Cout)[row * NC + col] = v + bvals[n];
        }
      }
    }
  }
}

// ---------------- flash attention (R16): per-half pipeline, v_exp_f32 ----------------
__global__ __launch_bounds__(256) void attn(
    const f16* __restrict__ Qp, const f16* __restrict__ Kp,
    const f16* __restrict__ Vt, f16* __restrict__ O)
{
  __shared__ f16 Ks[2][64 * 64];
  __shared__ f16 Vs[2][64 * 64];
  const int tid = threadIdx.x;
  const int w = tid >> 6, lane = tid & 63;
  const int c = lane & 31, h = lane >> 5;
  const int qt = blockIdx.x, hh = blockIdx.y, b = blockIdx.z;
  const size_t qrow = (size_t)b * 4096 + qt * 128 + w * 32 + c;

  f16x8 qf[4];
#pragma unroll
  for (int ks = 0; ks < 4; ++ks)
    qf[ks] = *(const f16x8*)(Qp + qrow * NC + hh * 64 + ks * 16 + 8 * h);

  f32x16 oa0 = {}, oa1 = {};
  float l_run = 0.f;

  const int r0 = tid >> 3, k0b = tid & 7;
  const int r1 = (tid + 256) >> 3, k1b = tid & 7;
  const f16* ks0 = Kp + ((size_t)b * 512 + r0) * NC + hh * 64 + ((k0b ^ (r0 & 7)) * 8);
  const f16* ks1 = Kp + ((size_t)b * 512 + r1) * NC + hh * 64 + ((k1b ^ (r1 & 7)) * 8);
  const f16* vs0 = Vt + ((size_t)b * NC + hh * 64 + r0) * 512 + ((k0b ^ (r0 & 7)) * 8);
  const f16* vs1 = Vt + ((size_t)b * NC + hh * 64 + r1) * 512 + ((k1b ^ (r1 & 7)) * 8);
  gll16(ks0, (char*)&Ks[0][0] + tid * 16);
  gll16(ks1, (char*)&Ks[0][0] + (tid + 256) * 16);
  gll16(vs0, (char*)&Vs[0][0] + tid * 16);
  gll16(vs1, (char*)&Vs[0][0] + (tid + 256) * 16);

  int buf = 0;
  for (int ch = 0; ch < 8; ++ch) {
    __syncthreads();
    if (ch < 7) {
      gll16(ks0 + (size_t)(ch + 1) * 64 * NC, (char*)&Ks[buf ^ 1][0] + tid * 16);
      gll16(ks1 + (size_t)(ch + 1) * 64 * NC, (char*)&Ks[buf ^ 1][0] + (tid + 256) * 16);
      gll16(vs0 + (ch + 1) * 64, (char*)&Vs[buf ^ 1][0] + tid * 16);
      gll16(vs1 + (ch + 1) * 64, (char*)&Vs[buf ^ 1][0] + (tid + 256) * 16);
    }
    const char* kb = (const char*)&Ks[buf][0];
    const char* vb = (const char*)&Vs[buf][0];
#pragma unroll
    for (int half = 0; half < 2; ++half) {
      f32x16 st = {};
#pragma unroll
      for (int ks = 0; ks < 4; ++ks) {
        const int bo = ((2 * ks + h) ^ (c & 7)) * 16;
        const f16x8 kf = *(const f16x8*)(kb + (32 * half + c) * 128 + bo);
        st = MFMA32(kf, qf[ks], st);
      }
      u32 pk[8];
      float ps0 = 0.f, ps1 = 0.f;
#pragma unroll
      for (int t = 0; t < 8; ++t) {
        const float a0 = __builtin_amdgcn_exp2f(st[2 * t]);
        const float a1 = __builtin_amdgcn_exp2f(st[2 * t + 1]);
        ps0 += a0; ps1 += a1;
        pk[t] = pkf16(a0, a1);
      }
      l_run += ps0 + ps1;
#pragma unroll
      for (int ss = 0; ss < 2; ++ss) {
        const int s = half * 2 + ss, tb = ss * 4;
        const u32 xs = h ? pk[tb + 0] : pk[tb + 2];
        const u32 ys = h ? pk[tb + 1] : pk[tb + 3];
        const u32 rx = __shfl_xor(xs, 32);
        const u32 ry = __shfl_xor(ys, 32);
        u32x4 fi;
        fi[0] = h ? rx : pk[tb + 0];
        fi[1] = h ? ry : pk[tb + 1];
        fi[2] = h ? pk[tb + 2] : rx;
        fi[3] = h ? pk[tb + 3] : ry;
        const f16x8 pfrag = __builtin_bit_cast(f16x8, fi);
        const int bo = ((2 * s + h) ^ (c & 7)) * 16;
        const f16x8 v0 = *(const f16x8*)(vb + c * 128 + bo);
        const f16x8 v1 = *(const f16x8*)(vb + (32 + c) * 128 + bo);
        oa0 = MFMA32(v0, pfrag, oa0);
        oa1 = MFMA32(v1, pfrag, oa1);
      }
    }
    buf ^= 1;
  }
  const float ltot = l_run + __shfl_xor(l_run, 32);
  const float linv = 1.0f / ltot;
  f16* orow = O + qrow * NC + hh * 64;
#pragma unroll
  for (int dt = 0; dt < 2; ++dt) {
#pragma unroll
    for (int qd = 0; qd < 4; ++qd) {
      const float v0 = (dt ? oa1[4 * qd + 0] : oa0[4 * qd + 0]) * linv;
      const float v1 = (dt ? oa1[4 * qd + 1] : oa0[4 * qd + 1]) * linv;
      const float v2 = (dt ? oa1[4 * qd + 2] : oa0[4 * qd + 2]) * linv;
      const float v3 = (dt ? oa1[4 * qd + 3] : oa0[4 * qd + 3]) * linv;
      uint2 pr; pr.x = pkf16(v0, v1); pr.y = pkf16(v2, v3);
      *(uint2*)(orow + dt * 32 + 8 * qd + 4 * h) = pr;
    }
  }
}

// ---------------- launch ----------------
extern "C" void kernel_launch(void* const* d_in, const int* in_sizes, int n_in,
                              void* d_out, int out_size, void* d_ws, size_t ws_size,
                              hipStream_t stream) {
  const float* x   = (const float*)d_in[0];
  const float* cqw = (const float*)d_in[1];
  const float* ckw = (const float*)d_in[2];
  const float* cvw = (const float*)d_in[3];
  const float* bqg = (const float*)d_in[4],  *bqb = (const float*)d_in[5];
  const float* bqm = (const float*)d_in[6],  *bqv = (const float*)d_in[7];
  const float* bkg = (const float*)d_in[8],  *bkb = (const float*)d_in[9];
  const float* bkm = (const float*)d_in[10], *bkv = (const float*)d_in[11];
  const float* bvg = (const float*)d_in[12], *bvb = (const float*)d_in[13];
  const float* bvm = (const float*)d_in[14], *bvv = (const float*)d_in[15];
  const float* wq = (const float*)d_in[16];
  const float* wk = (const float*)d_in[17];
  const float* wv = (const float*)d_in[18];
  const float* pw = (const float*)d_in[19];
  const float* pb = (const float*)d_in[20];

  f16* q_tok = (f16*)d_out;                              // lo half (25 MB)
  f16* Qp    = (f16*)((char*)d_out + 25165824);          // hi half (25 MB)

  char* ws = (char*)d_ws;
  f16* wq_h  = (f16*)(ws + 0);
  f16* wk_h  = (f16*)(ws + 294912);
  f16* wv_h  = (f16*)(ws + 589824);
  f16* pw_h  = (f16*)(ws + 884736);
  f16* k_tok = (f16*)(ws + 1179648);
  f16* v_tok = (f16*)(ws + 4325376);
  f16* Kp    = (f16*)(ws + 7471104);
  f16* Vt    = (f16*)(ws + 10616832);
  f16* Oi    = (f16*)(ws + 13762560);
  float* wqT = (float*)(ws + 38928384);   // 41472 B each
  float* wkT = (float*)(ws + 38969856);
  float* wvT = (float*)(ws + 39011328);
  float* betq = (float*)(ws + 39052800);  // 1536 B each
  float* betk = (float*)(ws + 39054336);
  float* betv = (float*)(ws + 39055872);  // ws total 39,057,408 B

  const float scq = 0.051031036307982884f * 1.4426950408889634f; // 384^-0.5 * log2(e)
  cvt_w<<<dim3(576), dim3(256), 0, stream>>>(wq, wk, wv, pw, wq_h, wk_h, wv_h, pw_h,
                                             147456, scq);
  cvt_wt<<<dim3(27), dim3(384), 0, stream>>>(
      cqw, ckw, cvw,
      bqg, bqb, bqm, bqv, bkg, bkb, bkm, bkv, bvg, bvb, bvm, bvv,
      wqT, wkT, wvT, betq, betk, betv);
  conv_fused<<<dim3(192, 8, 2), dim3(128), 0, stream>>>(
      x, wqT, wkT, wvT, betq, betk, betv, q_tok, k_tok, v_tok);
  gemm_bt<0><<<dim3(3, 256), dim3(256), 0, stream>>>(q_tok, wq_h, Qp, nullptr);
  gemm_bt<0><<<dim3(3, 32),  dim3(256), 0, stream>>>(k_tok, wk_h, Kp, nullptr);
  gemm_bt<1><<<dim3(3, 32),  dim3(256), 0, stream>>>(v_tok, wv_h, Vt, nullptr);
  attn<<<dim3(32, 6, 8), dim3(256), 0, stream>>>(Qp, Kp, Vt, Oi);
  gemm_bt<2><<<dim3(3, 256), dim3(256), 0, stream>>>(Oi, pw_h, d_out, pb);
}